// Round 17
// baseline (846.106 us; speedup 1.0000x reference)
//
#include <hip/hip_runtime.h>
#include <hip/hip_bf16.h>
#include <math.h>

#define B_ 64
#define N_ 1024
#define E_ 524288
#define EPG_ 8192
#define K1_ 512
#define K2_ 256
#define K3_ 128
#define M0_ 65536
#define M1_ 32768
#define M2_ 16384
#define M3_ 8192

static __device__ __forceinline__ float eluf(float x){ return x > 0.f ? x : expm1f(x); }
// bf16 RNE pack/unpack. All math fp32; only storage bf16.
static __device__ __forceinline__ unsigned short f2bf(float f){
  union{float f; unsigned u;} v; v.f=f;
  unsigned u = v.u + 0x7FFF + ((v.u>>16)&1);
  return (unsigned short)(u>>16);
}
static __device__ __forceinline__ float bf2f(unsigned short h){
  union{unsigned u; float f;} v; v.u = ((unsigned)h)<<16;
  return v.f;
}
static __device__ __forceinline__ float4 ldU4(const unsigned short* __restrict__ p, size_t idx){
  ushort4 r = *(const ushort4*)(p + idx);
  float4 o; o.x=bf2f(r.x); o.y=bf2f(r.y); o.z=bf2f(r.z); o.w=bf2f(r.w);
  return o;
}
static __device__ __forceinline__ void stU4(unsigned short* __restrict__ p, size_t idx, float4 v){
  ushort4 h; h.x=f2bf(v.x); h.y=f2bf(v.y); h.z=f2bf(v.z); h.w=f2bf(v.w);
  *(ushort4*)(p + idx) = h;
}

// Tiled GEMM (round-9 proven schedule, bf16 storage). Layers 2-7.
// MODE 1: H = elu(Xh[perm[m]]*vals[m])@W ; MODE 2: H = elu(concat(Xd,Xh))@W
template<int BM,int BN,int MODE>
__global__ __launch_bounds__(256) void k_mm(const unsigned short* __restrict__ Xh,
    const float* __restrict__ W, unsigned short* __restrict__ H, int M, int K, int N,
    const int* __restrict__ perm, const float* __restrict__ vals,
    const unsigned short* __restrict__ Xd, const int* __restrict__ orig,
    const int* __restrict__ rm, int WD4){
  constexpr int TX = BN/4;
  constexpr int TY = 256/TX;
  constexpr int RM = BM/TY;
  __shared__ float Xs[BM][36];
  __shared__ float Ws[32][BN];
  const int t = threadIdx.x;
  const int tx = t % TX, ty = t / TX;
  const int m0 = blockIdx.x*BM, n0 = blockIdx.y*BN;
  float acc[RM][4];
  #pragma unroll
  for (int r=0;r<RM;++r){acc[r][0]=0.f;acc[r][1]=0.f;acc[r][2]=0.f;acc[r][3]=0.f;}
  for (int k0=0;k0<K;k0+=32){
    #pragma unroll
    for (int l=0;l<BM/32;++l){
      int fi=l*256+t, row=fi>>3, q=fi&7;
      int m = m0+row;
      int c4 = (k0>>2)+q;
      float4 v;
      if (MODE==1){
        int pm = perm[m]; float vv = vals[m];
        float4 h = ldU4(Xh, (size_t)pm*K + (c4<<2));
        v.x=eluf(h.x*vv); v.y=eluf(h.y*vv); v.z=eluf(h.z*vv); v.w=eluf(h.w*vv);
      } else {
        if (c4 < WD4){
          int o = orig ? orig[m] : m;
          int j = rm[o];
          if (j>=0){
            float4 h = ldU4(Xd, ((size_t)j*WD4 + c4)*4);
            v.x=eluf(h.x); v.y=eluf(h.y); v.z=eluf(h.z); v.w=eluf(h.w);
          } else { v.x=0.f;v.y=0.f;v.z=0.f;v.w=0.f; }
        } else {
          int ws4 = (K>>2) - WD4;
          float4 h = ldU4(Xh, ((size_t)m*ws4 + (c4-WD4))*4);
          v.x=eluf(h.x); v.y=eluf(h.y); v.z=eluf(h.z); v.w=eluf(h.w);
        }
      }
      *(float4*)(&Xs[row][q*4]) = v;
    }
    #pragma unroll
    for (int l=0;l<BN/32;++l){
      int fi=l*256+t, wrow=fi/(BN/4), wq=fi%(BN/4);
      *(float4*)(&Ws[wrow][wq*4]) = *(const float4*)(W + (size_t)(k0+wrow)*N + n0 + wq*4);
    }
    __syncthreads();
    #pragma unroll
    for (int kq=0;kq<32;kq+=4){
      float4 xv[RM];
      #pragma unroll
      for (int r=0;r<RM;++r) xv[r] = *(const float4*)(&Xs[ty*RM+r][kq]);
      #pragma unroll
      for (int j=0;j<4;++j){
        float4 wv = *(const float4*)(&Ws[kq+j][tx*4]);
        #pragma unroll
        for (int r=0;r<RM;++r){
          float xs = (j==0)?xv[r].x:(j==1)?xv[r].y:(j==2)?xv[r].z:xv[r].w;
          acc[r][0]=fmaf(xs,wv.x,acc[r][0]);
          acc[r][1]=fmaf(xs,wv.y,acc[r][1]);
          acc[r][2]=fmaf(xs,wv.z,acc[r][2]);
          acc[r][3]=fmaf(xs,wv.w,acc[r][3]);
        }
      }
    }
    __syncthreads();
  }
  #pragma unroll
  for (int r=0;r<RM;++r){
    int m = m0 + ty*RM + r;
    float4 h; h.x=acc[r][0];h.y=acc[r][1];h.z=acc[r][2];h.w=acc[r][3];
    stU4(H, (size_t)m*N + n0 + tx*4, h);
  }
}

// ---- role-fused: blocks 0..511 run layer-1 GEMM (fp32 x -> bf16 H),
// blocks 512..575 build the per-graph CSR + zero the pool counters.
// The two roles are data-independent; CSR overlaps under the GEMM.
__global__ __launch_bounds__(256) void k_csr_mm1(const float* __restrict__ X,
    const float* __restrict__ W, unsigned short* __restrict__ H,
    const int* __restrict__ src0, const int* __restrict__ dst0,
    int* __restrict__ rowptr, int* __restrict__ col, float* __restrict__ dinv,
    int* __restrict__ cntA, int* __restrict__ cntB, int* __restrict__ cntC){
  const int t = threadIdx.x;
  if (blockIdx.x < 512){
    constexpr int BM=128, BN=32, TX=BN/4, TY=256/TX, RM=BM/TY;
    constexpr int K=128, N=32;
    __shared__ float Xs[BM][36];
    __shared__ float Ws[32][BN];
    const int tx = t % TX, ty = t / TX;
    const int m0 = blockIdx.x*BM;
    float acc[RM][4];
    #pragma unroll
    for (int r=0;r<RM;++r){acc[r][0]=0.f;acc[r][1]=0.f;acc[r][2]=0.f;acc[r][3]=0.f;}
    for (int k0=0;k0<K;k0+=32){
      #pragma unroll
      for (int l=0;l<BM/32;++l){
        int fi=l*256+t, row=fi>>3, q=fi&7;
        *(float4*)(&Xs[row][q*4]) =
            *(const float4*)(X + (size_t)(m0+row)*K + k0 + q*4);
      }
      {
        int wrow=t/(BN/4), wq=t%(BN/4);
        *(float4*)(&Ws[wrow][wq*4]) = *(const float4*)(W + (size_t)(k0+wrow)*N + wq*4);
      }
      __syncthreads();
      #pragma unroll
      for (int kq=0;kq<32;kq+=4){
        float4 xv[RM];
        #pragma unroll
        for (int r=0;r<RM;++r) xv[r] = *(const float4*)(&Xs[ty*RM+r][kq]);
        #pragma unroll
        for (int j=0;j<4;++j){
          float4 wv = *(const float4*)(&Ws[kq+j][tx*4]);
          #pragma unroll
          for (int r=0;r<RM;++r){
            float xs = (j==0)?xv[r].x:(j==1)?xv[r].y:(j==2)?xv[r].z:xv[r].w;
            acc[r][0]=fmaf(xs,wv.x,acc[r][0]);
            acc[r][1]=fmaf(xs,wv.y,acc[r][1]);
            acc[r][2]=fmaf(xs,wv.z,acc[r][2]);
            acc[r][3]=fmaf(xs,wv.w,acc[r][3]);
          }
        }
      }
      __syncthreads();
    }
    #pragma unroll
    for (int r=0;r<RM;++r){
      int m = m0 + ty*RM + r;
      float4 h; h.x=acc[r][0];h.y=acc[r][1];h.z=acc[r][2];h.w=acc[r][3];
      stU4(H, (size_t)m*N + tx*4, h);
    }
  } else {
    __shared__ int ldeg[1024];
    __shared__ int pspart[256];
    __shared__ int lcur[1024];
    const int g = blockIdx.x - 512;
    const int ebase = g*EPG_, nbase = g<<10;
    for (int v=t; v<1024; v+=256) ldeg[v]=0;
    __syncthreads();
    #pragma unroll
    for (int i=0;i<EPG_/256;++i){
      int e = ebase + i*256 + t;
      atomicAdd(&ldeg[dst0[e]-nbase], 1);
    }
    __syncthreads();
    int s4[4]; int sum=0;
    #pragma unroll
    for (int i=0;i<4;++i){ s4[i]=ldeg[t*4+i]; sum+=s4[i]; }
    pspart[t]=sum; __syncthreads();
    for (int o=1;o<256;o<<=1){
      int v2 = (t>=o)?pspart[t-o]:0;
      __syncthreads(); pspart[t]+=v2; __syncthreads();
    }
    int run = pspart[t]-sum;
    #pragma unroll
    for (int i=0;i<4;++i){
      int node = t*4+i;
      rowptr[nbase+node] = ebase + run;
      lcur[node] = run;
      dinv[nbase+node] = rsqrtf((float)s4[i] + 2.f);
      run += s4[i];
    }
    if (g == B_-1 && t == 255) rowptr[M0_] = E_;
    __syncthreads();
    #pragma unroll
    for (int i=0;i<EPG_/256;++i){
      int e = ebase + i*256 + t;
      int dl = dst0[e]-nbase;
      int p = atomicAdd(&lcur[dl], 1);
      col[ebase+p] = src0[e];
    }
    if (t==0){ cntA[g]=0; cntB[g]=0; cntC[g]=0; }
  }
}

// ---- fused per-graph pool phase (runs in the LAST gather block of each graph)
static __device__ void pool_phase(int g, int npg, const float* __restrict__ score,
    const int* __restrict__ prevOrig, const int* __restrict__ rowptr0,
    const int* __restrict__ col0, int* __restrict__ perm, float* __restrict__ vals,
    int* __restrict__ orig, int* __restrict__ rm, float* __restrict__ dinv,
    float* ss, int* si){
  const int t = threadIdx.x;
  for (int v=t; v<npg; v+=256){ ss[v]=score[g*npg+v]; si[v]=v; }
  for (int v=t; v<1024; v+=256) rm[(g<<10)+v] = -1;
  __syncthreads();
  for (int k=2;k<=npg;k<<=1){
    for (int j=k>>1;j>0;j>>=1){
      for (int v=t; v<npg; v+=256){
        if ((v & j)==0){
          int ix = v|j;
          float s1=ss[v], s2=ss[ix]; int i1=si[v], i2=si[ix];
          bool aAfterB = (s1 < s2) || (s1==s2 && i1 > i2);
          bool sw = ((v & k)==0) ? aAfterB : !aAfterB;
          if (sw){ ss[v]=s2; si[v]=i2; ss[ix]=s1; si[ix]=i1; }
        }
      }
      __syncthreads();
    }
  }
  const int KK = npg>>1;
  for (int v=t; v<KK; v+=256){
    int pl = g*npg + si[v];
    perm[g*KK+v] = pl;
    vals[g*KK+v] = ss[v];
    int o = prevOrig ? prevOrig[pl] : pl;
    orig[g*KK+v] = o;
    rm[o] = g*KK + v;
  }
  __syncthreads();
  for (int v=t; v<KK; v+=256){
    int o = orig[g*KK+v];
    int beg = rowptr0[o], end = rowptr0[o+1];
    int d = 0;
    for (int j=beg;j<end;++j) d += (rm[col0[j]] >= 0) ? 1 : 0;
    dinv[g*KK+v] = rsqrtf((float)d + 2.f);
  }
}

// ---- level-0 GCN aggregation; optional fused score + fused per-graph pool
template<int F, bool SCORE, bool POOL>
__global__ __launch_bounds__(256) void k_gather(const int* __restrict__ rowptr,
    const int* __restrict__ col, const float* __restrict__ dinv,
    const unsigned short* __restrict__ H, const float* __restrict__ bias,
    unsigned short* __restrict__ OUT, int M,
    const float* __restrict__ p, float* __restrict__ score,
    int npg, const int* __restrict__ prevOrig,
    int* __restrict__ permOut, float* __restrict__ valsOut,
    int* __restrict__ origOut, int* __restrict__ rmOut,
    float* __restrict__ dinvOut, int* __restrict__ cnt){
  constexpr int FQ = F/4;
  int i = blockIdx.x*256+threadIdx.x;
  if (i < M*FQ){
    int n = i/FQ, q = i - (i/FQ)*FQ;
    int beg = rowptr[n], end = rowptr[n+1];
    float4 acc; acc.x=0.f;acc.y=0.f;acc.z=0.f;acc.w=0.f;
    for (int j=beg;j<end;++j){
      int s = col[j];
      float c = dinv[s];
      float4 h = ldU4(H, (size_t)s*F + q*4);
      acc.x=fmaf(c,h.x,acc.x); acc.y=fmaf(c,h.y,acc.y);
      acc.z=fmaf(c,h.z,acc.z); acc.w=fmaf(c,h.w,acc.w);
    }
    float dn = dinv[n];
    float sc = 2.f*dn*dn;
    float4 hn = ldU4(H, (size_t)n*F + q*4);
    float4 bv = *(const float4*)(bias + q*4);
    float4 o;
    o.x = eluf(fmaf(sc,hn.x,fmaf(dn,acc.x,bv.x)));
    o.y = eluf(fmaf(sc,hn.y,fmaf(dn,acc.y,bv.y)));
    o.z = eluf(fmaf(sc,hn.z,fmaf(dn,acc.z,bv.z)));
    o.w = eluf(fmaf(sc,hn.w,fmaf(dn,acc.w,bv.w)));
    stU4(OUT, (size_t)n*F + q*4, o);
    if (SCORE){
      float4 pv = *(const float4*)(p + q*4);
      float dot = o.x*pv.x + o.y*pv.y + o.z*pv.z + o.w*pv.w;
      float n2  = pv.x*pv.x + pv.y*pv.y + pv.z*pv.z + pv.w*pv.w;
      #pragma unroll
      for (int mk=FQ>>1; mk>0; mk>>=1){
        dot += __shfl_xor(dot, mk);
        n2  += __shfl_xor(n2,  mk);
      }
      if (q==0) score[n] = tanhf(dot * rsqrtf(n2));
    }
  }
  if (POOL){
    __shared__ float ss[1024];
    __shared__ int si[1024];
    __shared__ int isLast;
    __threadfence();
    int g = blockIdx.x >> 5;           // 32 blocks per graph at every level
    if (threadIdx.x==0){
      int old = atomicAdd(&cnt[g], 1);
      isLast = (old == 31) ? 1 : 0;
    }
    __syncthreads();
    if (!isLast) return;
    __threadfence();
    pool_phase(g, npg, score, prevOrig, rowptr, col, permOut, valsOut,
               origOut, rmOut, dinvOut, ss, si);
  }
}

// ---- pooled-level GCN aggregation through rm filter; optional score+pool
template<int F, bool SCORE, bool POOL>
__global__ __launch_bounds__(256) void k_gather_rm(const int* __restrict__ orig,
    const int* __restrict__ rowptr0, const int* __restrict__ col0,
    const int* __restrict__ rm, const float* __restrict__ dinv,
    const unsigned short* __restrict__ H, const float* __restrict__ bias,
    unsigned short* __restrict__ OUT, int M,
    const float* __restrict__ p, float* __restrict__ score,
    int npg, const int* __restrict__ prevOrig,
    int* __restrict__ permOut, float* __restrict__ valsOut,
    int* __restrict__ origOut, int* __restrict__ rmOut,
    float* __restrict__ dinvOut, int* __restrict__ cnt){
  constexpr int FQ = F/4;
  int i = blockIdx.x*256+threadIdx.x;
  if (i < M*FQ){
    int n = i/FQ, q = i - (i/FQ)*FQ;
    int o = orig[n];
    int beg = rowptr0[o], end = rowptr0[o+1];
    float4 acc; acc.x=0.f;acc.y=0.f;acc.z=0.f;acc.w=0.f;
    for (int j=beg;j<end;++j){
      int s = rm[col0[j]];
      if (s >= 0){
        float c = dinv[s];
        float4 h = ldU4(H, (size_t)s*F + q*4);
        acc.x=fmaf(c,h.x,acc.x); acc.y=fmaf(c,h.y,acc.y);
        acc.z=fmaf(c,h.z,acc.z); acc.w=fmaf(c,h.w,acc.w);
      }
    }
    float dn = dinv[n];
    float sc = 2.f*dn*dn;
    float4 hn = ldU4(H, (size_t)n*F + q*4);
    float4 bv = *(const float4*)(bias + q*4);
    float4 ov;
    ov.x = eluf(fmaf(sc,hn.x,fmaf(dn,acc.x,bv.x)));
    ov.y = eluf(fmaf(sc,hn.y,fmaf(dn,acc.y,bv.y)));
    ov.z = eluf(fmaf(sc,hn.z,fmaf(dn,acc.z,bv.z)));
    ov.w = eluf(fmaf(sc,hn.w,fmaf(dn,acc.w,bv.w)));
    stU4(OUT, (size_t)n*F + q*4, ov);
    if (SCORE){
      float4 pv = *(const float4*)(p + q*4);
      float dot = ov.x*pv.x + ov.y*pv.y + ov.z*pv.z + ov.w*pv.w;
      float n2  = pv.x*pv.x + pv.y*pv.y + pv.z*pv.z + pv.w*pv.w;
      #pragma unroll
      for (int mk=FQ>>1; mk>0; mk>>=1){
        dot += __shfl_xor(dot, mk);
        n2  += __shfl_xor(n2,  mk);
      }
      if (q==0) score[n] = tanhf(dot * rsqrtf(n2));
    }
  }
  if (POOL){
    __shared__ float ss[1024];
    __shared__ int si[1024];
    __shared__ int isLast;
    __threadfence();
    int g = blockIdx.x >> 5;
    if (threadIdx.x==0){
      int old = atomicAdd(&cnt[g], 1);
      isLast = (old == 31) ? 1 : 0;
    }
    __syncthreads();
    if (!isLast) return;
    __threadfence();
    pool_phase(g, npg, score, prevOrig, rowptr0, col0, permOut, valsOut,
               origOut, rmOut, dinvOut, ss, si);
  }
}

// per-graph global max/mean pool over (1024,32) bf16 x13, MLP head + log_softmax
__global__ void k_head(const unsigned short* __restrict__ x13, const float* __restrict__ Wl,
                       const float* __restrict__ Wc, const float* __restrict__ bc,
                       float* __restrict__ out){
  __shared__ float smax[256], ssum[256];
  __shared__ float gv[64], g2[64], logit[10];
  int g = blockIdx.x, t = threadIdx.x;
  int f = t & 31, r0 = t >> 5;
  float mx = -3.4e38f, sm = 0.f;
  const unsigned short* base = x13 + (size_t)g*N_*32;
  for (int r=r0; r<N_; r+=8){ float v = bf2f(base[r*32+f]); mx = fmaxf(mx,v); sm += v; }
  smax[t]=mx; ssum[t]=sm; __syncthreads();
  if (t<128){ smax[t]=fmaxf(smax[t],smax[t+128]); ssum[t]+=ssum[t+128]; } __syncthreads();
  if (t<64){ smax[t]=fmaxf(smax[t],smax[t+64]); ssum[t]+=ssum[t+64]; } __syncthreads();
  if (t<32){
    float m2 = fmaxf(smax[t],smax[t+32]); float s2 = ssum[t]+ssum[t+32];
    gv[t] = eluf(m2); gv[32+t] = eluf(s2 * (1.f/N_));
  }
  __syncthreads();
  if (t<64){
    float acc=0.f;
    #pragma unroll
    for (int i2=0;i2<64;++i2) acc = fmaf(gv[i2], Wl[i2*64+t], acc);
    g2[t] = eluf(acc);
  }
  __syncthreads();
  if (t<10){
    float acc = bc[t];
    #pragma unroll
    for (int j=0;j<64;++j) acc = fmaf(g2[j], Wc[j*10+t], acc);
    logit[t] = acc;
  }
  __syncthreads();
  if (t==0){
    float m=-3.4e38f; for (int c=0;c<10;++c) m=fmaxf(m,logit[c]);
    float s=0.f; for (int c=0;c<10;++c) s += expf(logit[c]-m);
    float lse = m + logf(s);
    for (int c=0;c<10;++c) out[g*10+c] = logit[c]-lse;
  }
}

extern "C" void kernel_launch(void* const* d_in, const int* in_sizes, int n_in,
                              void* d_out, int out_size, void* d_ws, size_t ws_size,
                              hipStream_t stream){
  const float* x  = (const float*)d_in[0];
  const float* W1 = (const float*)d_in[1];
  const float* b1 = (const float*)d_in[2];
  const float* p1 = (const float*)d_in[3];
  const float* W2 = (const float*)d_in[4];
  const float* b2 = (const float*)d_in[5];
  const float* p2 = (const float*)d_in[6];
  const float* W3 = (const float*)d_in[7];
  const float* b3 = (const float*)d_in[8];
  const float* p3 = (const float*)d_in[9];
  const float* W4 = (const float*)d_in[10];
  const float* b4 = (const float*)d_in[11];
  const float* W5 = (const float*)d_in[12];
  const float* b5 = (const float*)d_in[13];
  const float* W6 = (const float*)d_in[14];
  const float* b6 = (const float*)d_in[15];
  const float* W7 = (const float*)d_in[16];
  const float* b7 = (const float*)d_in[17];
  const float* Wl = (const float*)d_in[18];
  const float* Wc = (const float*)d_in[19];
  const float* bc = (const float*)d_in[20];
  const int* src0 = (const int*)d_in[21];
  const int* dst0 = (const int*)d_in[22];
  float* out = (float*)d_out;

  char* wsp = (char*)d_ws;
  size_t off = 0;
  auto alloc = [&](size_t bytes)->char*{
    char* p = wsp + off;
    off += (bytes + 255) & ~(size_t)255;
    return p;
  };
  unsigned short* bufA = (unsigned short*)alloc((size_t)2097152*2);  // x1 / x13
  unsigned short* bufB = (unsigned short*)alloc((size_t)2097152*2);  // x3
  unsigned short* bufC = (unsigned short*)alloc((size_t)2097152*2);  // x5 / x11
  unsigned short* bufD = (unsigned short*)alloc((size_t)2097152*2);  // x7 / x9
  unsigned short* bufH = (unsigned short*)alloc((size_t)2097152*2);  // pre-norm H
  float* score= (float*)alloc((size_t)M0_*4);
  float* vals2= (float*)alloc((size_t)M1_*4);
  float* vals4= (float*)alloc((size_t)M2_*4);
  float* vals6= (float*)alloc((size_t)M3_*4);
  int* idx2 = (int*)alloc((size_t)M1_*4);
  int* idx4 = (int*)alloc((size_t)M2_*4);
  int* idx6 = (int*)alloc((size_t)M3_*4);
  int* orig4 = (int*)alloc((size_t)M2_*4);
  int* orig6 = (int*)alloc((size_t)M3_*4);
  int* rm02 = (int*)alloc((size_t)M0_*4);
  int* rm04 = (int*)alloc((size_t)M0_*4);
  int* rm06 = (int*)alloc((size_t)M0_*4);
  int* col0 = (int*)alloc((size_t)E_*4);
  int* rowptr0 = (int*)alloc((size_t)(M0_+1)*4);
  float* dinv0 = (float*)alloc((size_t)M0_*4);
  float* dinv2 = (float*)alloc((size_t)M1_*4);
  float* dinv4 = (float*)alloc((size_t)M2_*4);
  float* dinv6 = (float*)alloc((size_t)M3_*4);
  int* cntA = (int*)alloc((size_t)B_*4);
  int* cntB = (int*)alloc((size_t)B_*4);
  int* cntC = (int*)alloc((size_t)B_*4);

  auto NB = [](int total){ return (total+255)/256; };

  // ---- fused: layer-1 GEMM (blocks 0-511) ∥ per-graph CSR (blocks 512-575)
  k_csr_mm1<<<576,256,0,stream>>>(x, W1, bufH, src0, dst0, rowptr0, col0, dinv0,
                                  cntA, cntB, cntC);

  // ---- x1 = gather(H1) + score1 + FUSED pool1 (last block per graph)
  k_gather<32,true,true><<<NB(M0_*8),256,0,stream>>>(rowptr0, col0, dinv0, bufH, b1,
      bufA, M0_, p1, score, 1024, nullptr, idx2, vals2, idx2, rm02, dinv2, cntA);

  // ---- layer 2 (fused pool staging) -> H2; x3 = gather + score2 + pool2
  k_mm<64,64,1><<<dim3(M1_/64,1),256,0,stream>>>(bufA, W2, bufH, M1_, 32, 64,
      idx2, vals2, nullptr,nullptr,nullptr,0);
  k_gather_rm<64,true,true><<<NB(M1_*16),256,0,stream>>>(idx2, rowptr0, col0, rm02,
      dinv2, bufH, b2, bufB, M1_, p2, score, 512, idx2, idx4, vals4, orig4, rm04,
      dinv4, cntB);

  // ---- layer 3 -> H3; x5 = gather + score3 + pool3
  k_mm<64,64,1><<<dim3(M2_/64,2),256,0,stream>>>(bufB, W3, bufH, M2_, 64, 128,
      idx4, vals4, nullptr,nullptr,nullptr,0);
  k_gather_rm<128,true,true><<<NB(M2_*32),256,0,stream>>>(orig4, rowptr0, col0, rm04,
      dinv4, bufH, b3, bufC, M2_, p3, score, 256, orig4, idx6, vals6, orig6, rm06,
      dinv6, cntC);

  // ---- layer 4 -> x7 (bufD)
  k_mm<64,64,1><<<dim3(M3_/64,4),256,0,stream>>>(bufC, W4, bufH, M3_, 128, 256,
      idx6, vals6, nullptr,nullptr,nullptr,0);
  k_gather_rm<256,false,false><<<NB(M3_*64),256,0,stream>>>(orig6, rowptr0, col0, rm06,
      dinv6, bufH, b4, bufD, M3_, nullptr, nullptr, 0, nullptr, nullptr, nullptr,
      nullptr, nullptr, nullptr, nullptr);

  // ---- layer 5 (fused concat staging) -> x9 (bufD)
  k_mm<64,64,2><<<dim3(M2_/64,2),256,0,stream>>>(bufC, W5, bufH, M2_, 384, 128,
      nullptr,nullptr, bufD, orig4, rm06, 64);
  k_gather_rm<128,false,false><<<NB(M2_*32),256,0,stream>>>(orig4, rowptr0, col0, rm04,
      dinv4, bufH, b5, bufD, M2_, nullptr, nullptr, 0, nullptr, nullptr, nullptr,
      nullptr, nullptr, nullptr, nullptr);

  // ---- layer 6 -> x11 (bufC)
  k_mm<64,64,2><<<dim3(M1_/64,1),256,0,stream>>>(bufB, W6, bufH, M1_, 192, 64,
      nullptr,nullptr, bufD, idx2, rm04, 32);
  k_gather_rm<64,false,false><<<NB(M1_*16),256,0,stream>>>(idx2, rowptr0, col0, rm02,
      dinv2, bufH, b6, bufC, M1_, nullptr, nullptr, 0, nullptr, nullptr, nullptr,
      nullptr, nullptr, nullptr, nullptr);

  // ---- layer 7 -> x13 (bufA)
  k_mm<128,32,2><<<dim3(M0_/128,1),256,0,stream>>>(bufA, W7, bufH, M0_, 96, 32,
      nullptr,nullptr, bufC, nullptr, rm02, 16);
  k_gather<32,false,false><<<NB(M0_*8),256,0,stream>>>(rowptr0, col0, dinv0, bufH, b7,
      bufA, M0_, nullptr, nullptr, 0, nullptr, nullptr, nullptr, nullptr, nullptr,
      nullptr, nullptr);

  // ---- head
  k_head<<<B_,256,0,stream>>>(bufA, Wl, Wc, bc, out);

  (void)in_sizes; (void)n_in; (void)out_size; (void)ws_size;
}

// Round 18
// 327.879 us; speedup vs baseline: 2.5805x; 2.5805x over previous
//
#include <hip/hip_runtime.h>
#include <hip/hip_bf16.h>
#include <math.h>

#define B_ 64
#define N_ 1024
#define E_ 524288
#define EPG_ 8192
#define K1_ 512
#define K2_ 256
#define K3_ 128
#define M0_ 65536
#define M1_ 32768
#define M2_ 16384
#define M3_ 8192

static __device__ __forceinline__ float eluf(float x){ return x > 0.f ? x : expm1f(x); }
// bf16 RNE pack/unpack. All math fp32; only storage bf16.
static __device__ __forceinline__ unsigned short f2bf(float f){
  union{float f; unsigned u;} v; v.f=f;
  unsigned u = v.u + 0x7FFF + ((v.u>>16)&1);
  return (unsigned short)(u>>16);
}
static __device__ __forceinline__ float bf2f(unsigned short h){
  union{unsigned u; float f;} v; v.u = ((unsigned)h)<<16;
  return v.f;
}
static __device__ __forceinline__ float4 ldU4(const unsigned short* __restrict__ p, size_t idx){
  ushort4 r = *(const ushort4*)(p + idx);
  float4 o; o.x=bf2f(r.x); o.y=bf2f(r.y); o.z=bf2f(r.z); o.w=bf2f(r.w);
  return o;
}
static __device__ __forceinline__ void stU4(unsigned short* __restrict__ p, size_t idx, float4 v){
  ushort4 h; h.x=f2bf(v.x); h.y=f2bf(v.y); h.z=f2bf(v.z); h.w=f2bf(v.w);
  *(ushort4*)(p + idx) = h;
}

// Tiled GEMM (round-9 proven schedule, bf16 storage). Layers 2-7.
// MODE 1: H = elu(Xh[perm[m]]*vals[m])@W ; MODE 2: H = elu(concat(Xd,Xh))@W
template<int BM,int BN,int MODE>
__global__ __launch_bounds__(256) void k_mm(const unsigned short* __restrict__ Xh,
    const float* __restrict__ W, unsigned short* __restrict__ H, int M, int K, int N,
    const int* __restrict__ perm, const float* __restrict__ vals,
    const unsigned short* __restrict__ Xd, const int* __restrict__ orig,
    const int* __restrict__ rm, int WD4){
  constexpr int TX = BN/4;
  constexpr int TY = 256/TX;
  constexpr int RM = BM/TY;
  __shared__ float Xs[BM][36];
  __shared__ float Ws[32][BN];
  const int t = threadIdx.x;
  const int tx = t % TX, ty = t / TX;
  const int m0 = blockIdx.x*BM, n0 = blockIdx.y*BN;
  float acc[RM][4];
  #pragma unroll
  for (int r=0;r<RM;++r){acc[r][0]=0.f;acc[r][1]=0.f;acc[r][2]=0.f;acc[r][3]=0.f;}
  for (int k0=0;k0<K;k0+=32){
    #pragma unroll
    for (int l=0;l<BM/32;++l){
      int fi=l*256+t, row=fi>>3, q=fi&7;
      int m = m0+row;
      int c4 = (k0>>2)+q;
      float4 v;
      if (MODE==1){
        int pm = perm[m]; float vv = vals[m];
        float4 h = ldU4(Xh, (size_t)pm*K + (c4<<2));
        v.x=eluf(h.x*vv); v.y=eluf(h.y*vv); v.z=eluf(h.z*vv); v.w=eluf(h.w*vv);
      } else {
        if (c4 < WD4){
          int o = orig ? orig[m] : m;
          int j = rm[o];
          if (j>=0){
            float4 h = ldU4(Xd, ((size_t)j*WD4 + c4)*4);
            v.x=eluf(h.x); v.y=eluf(h.y); v.z=eluf(h.z); v.w=eluf(h.w);
          } else { v.x=0.f;v.y=0.f;v.z=0.f;v.w=0.f; }
        } else {
          int ws4 = (K>>2) - WD4;
          float4 h = ldU4(Xh, ((size_t)m*ws4 + (c4-WD4))*4);
          v.x=eluf(h.x); v.y=eluf(h.y); v.z=eluf(h.z); v.w=eluf(h.w);
        }
      }
      *(float4*)(&Xs[row][q*4]) = v;
    }
    #pragma unroll
    for (int l=0;l<BN/32;++l){
      int fi=l*256+t, wrow=fi/(BN/4), wq=fi%(BN/4);
      *(float4*)(&Ws[wrow][wq*4]) = *(const float4*)(W + (size_t)(k0+wrow)*N + n0 + wq*4);
    }
    __syncthreads();
    #pragma unroll
    for (int kq=0;kq<32;kq+=4){
      float4 xv[RM];
      #pragma unroll
      for (int r=0;r<RM;++r) xv[r] = *(const float4*)(&Xs[ty*RM+r][kq]);
      #pragma unroll
      for (int j=0;j<4;++j){
        float4 wv = *(const float4*)(&Ws[kq+j][tx*4]);
        #pragma unroll
        for (int r=0;r<RM;++r){
          float xs = (j==0)?xv[r].x:(j==1)?xv[r].y:(j==2)?xv[r].z:xv[r].w;
          acc[r][0]=fmaf(xs,wv.x,acc[r][0]);
          acc[r][1]=fmaf(xs,wv.y,acc[r][1]);
          acc[r][2]=fmaf(xs,wv.z,acc[r][2]);
          acc[r][3]=fmaf(xs,wv.w,acc[r][3]);
        }
      }
    }
    __syncthreads();
  }
  #pragma unroll
  for (int r=0;r<RM;++r){
    int m = m0 + ty*RM + r;
    float4 h; h.x=acc[r][0];h.y=acc[r][1];h.z=acc[r][2];h.w=acc[r][3];
    stU4(H, (size_t)m*N + n0 + tx*4, h);
  }
}

// ---- role-fused: blocks 0..511 run layer-1 GEMM (fp32 x -> bf16 H),
// blocks 512..575 build the per-graph CSR. Roles are data-independent;
// the CSR work hides under the GEMM (fence-free — r17 proved fences kill).
__global__ __launch_bounds__(256) void k_csr_mm1(const float* __restrict__ X,
    const float* __restrict__ W, unsigned short* __restrict__ H,
    const int* __restrict__ src0, const int* __restrict__ dst0,
    int* __restrict__ rowptr, int* __restrict__ col, float* __restrict__ dinv){
  const int t = threadIdx.x;
  if (blockIdx.x < 512){
    constexpr int BM=128, BN=32, TX=BN/4, TY=256/TX, RM=BM/TY;
    constexpr int K=128, N=32;
    __shared__ float Xs[BM][36];
    __shared__ float Ws[32][BN];
    const int tx = t % TX, ty = t / TX;
    const int m0 = blockIdx.x*BM;
    float acc[RM][4];
    #pragma unroll
    for (int r=0;r<RM;++r){acc[r][0]=0.f;acc[r][1]=0.f;acc[r][2]=0.f;acc[r][3]=0.f;}
    for (int k0=0;k0<K;k0+=32){
      #pragma unroll
      for (int l=0;l<BM/32;++l){
        int fi=l*256+t, row=fi>>3, q=fi&7;
        *(float4*)(&Xs[row][q*4]) =
            *(const float4*)(X + (size_t)(m0+row)*K + k0 + q*4);
      }
      {
        int wrow=t/(BN/4), wq=t%(BN/4);
        *(float4*)(&Ws[wrow][wq*4]) = *(const float4*)(W + (size_t)(k0+wrow)*N + wq*4);
      }
      __syncthreads();
      #pragma unroll
      for (int kq=0;kq<32;kq+=4){
        float4 xv[RM];
        #pragma unroll
        for (int r=0;r<RM;++r) xv[r] = *(const float4*)(&Xs[ty*RM+r][kq]);
        #pragma unroll
        for (int j=0;j<4;++j){
          float4 wv = *(const float4*)(&Ws[kq+j][tx*4]);
          #pragma unroll
          for (int r=0;r<RM;++r){
            float xs = (j==0)?xv[r].x:(j==1)?xv[r].y:(j==2)?xv[r].z:xv[r].w;
            acc[r][0]=fmaf(xs,wv.x,acc[r][0]);
            acc[r][1]=fmaf(xs,wv.y,acc[r][1]);
            acc[r][2]=fmaf(xs,wv.z,acc[r][2]);
            acc[r][3]=fmaf(xs,wv.w,acc[r][3]);
          }
        }
      }
      __syncthreads();
    }
    #pragma unroll
    for (int r=0;r<RM;++r){
      int m = m0 + ty*RM + r;
      float4 h; h.x=acc[r][0];h.y=acc[r][1];h.z=acc[r][2];h.w=acc[r][3];
      stU4(H, (size_t)m*N + tx*4, h);
    }
  } else {
    __shared__ int ldeg[1024];
    __shared__ int pspart[256];
    __shared__ int lcur[1024];
    const int g = blockIdx.x - 512;
    const int ebase = g*EPG_, nbase = g<<10;
    for (int v=t; v<1024; v+=256) ldeg[v]=0;
    __syncthreads();
    #pragma unroll
    for (int i=0;i<EPG_/256;++i){
      int e = ebase + i*256 + t;
      atomicAdd(&ldeg[dst0[e]-nbase], 1);
    }
    __syncthreads();
    int s4[4]; int sum=0;
    #pragma unroll
    for (int i=0;i<4;++i){ s4[i]=ldeg[t*4+i]; sum+=s4[i]; }
    pspart[t]=sum; __syncthreads();
    for (int o=1;o<256;o<<=1){
      int v2 = (t>=o)?pspart[t-o]:0;
      __syncthreads(); pspart[t]+=v2; __syncthreads();
    }
    int run = pspart[t]-sum;
    #pragma unroll
    for (int i=0;i<4;++i){
      int node = t*4+i;
      rowptr[nbase+node] = ebase + run;
      lcur[node] = run;
      dinv[nbase+node] = rsqrtf((float)s4[i] + 2.f);
      run += s4[i];
    }
    if (g == B_-1 && t == 255) rowptr[M0_] = E_;
    __syncthreads();
    #pragma unroll
    for (int i=0;i<EPG_/256;++i){
      int e = ebase + i*256 + t;
      int dl = dst0[e]-nbase;
      int p = atomicAdd(&lcur[dl], 1);
      col[ebase+p] = src0[e];
    }
  }
}

// ---- fused per-graph pool (round-14/16 WIN kernel — standalone dispatch;
// r17 proved in-kernel fence-based fusion is far more expensive)
__global__ __launch_bounds__(1024) void k_pool(const float* __restrict__ score,
    int npg, int K, const int* __restrict__ prevOrig,
    const int* __restrict__ rowptr0, const int* __restrict__ col0,
    int* __restrict__ perm, float* __restrict__ vals,
    int* __restrict__ orig, int* __restrict__ rm, float* __restrict__ dinv){
  __shared__ float ss[1024]; __shared__ int si[1024];
  const int g = blockIdx.x, t = threadIdx.x;
  for (int i=t; i<1024; i+=npg) rm[(g<<10)+i] = -1;
  ss[t] = score[g*npg + t]; si[t] = t;
  __syncthreads();
  for (int k=2;k<=npg;k<<=1){
    for (int j=k>>1;j>0;j>>=1){
      int ixj = t ^ j;
      if (ixj > t){
        float s1=ss[t], s2=ss[ixj]; int i1=si[t], i2=si[ixj];
        bool aAfterB = (s1 < s2) || (s1==s2 && i1 > i2);
        bool sw = ((t & k)==0) ? aAfterB : !aAfterB;
        if (sw){ ss[t]=s2; si[t]=i2; ss[ixj]=s1; si[ixj]=i1; }
      }
      __syncthreads();
    }
  }
  int o = -1;
  if (t < K){
    int pl = g*npg + si[t];
    perm[g*K+t] = pl;
    vals[g*K+t] = ss[t];
    o = prevOrig ? prevOrig[pl] : pl;
    orig[g*K+t] = o;
    rm[o] = g*K + t;
  }
  __syncthreads();
  if (t < K){
    int beg = rowptr0[o], end = rowptr0[o+1];
    int d = 0;
    for (int j=beg;j<end;++j) d += (rm[col0[j]] >= 0) ? 1 : 0;
    dinv[g*K+t] = rsqrtf((float)d + 2.f);
  }
}

// ---- level-0 GCN aggregation (H bf16 in, OUT bf16); optional fused score
template<int F, bool SCORE>
__global__ __launch_bounds__(256) void k_gather(const int* __restrict__ rowptr,
    const int* __restrict__ col, const float* __restrict__ dinv,
    const unsigned short* __restrict__ H, const float* __restrict__ bias,
    unsigned short* __restrict__ OUT, int M,
    const float* __restrict__ p, float* __restrict__ score){
  constexpr int FQ = F/4;
  int i = blockIdx.x*256+threadIdx.x;
  if (i >= M*FQ) return;
  int n = i/FQ, q = i - (i/FQ)*FQ;
  int beg = rowptr[n], end = rowptr[n+1];
  float4 acc; acc.x=0.f;acc.y=0.f;acc.z=0.f;acc.w=0.f;
  for (int j=beg;j<end;++j){
    int s = col[j];
    float c = dinv[s];
    float4 h = ldU4(H, (size_t)s*F + q*4);
    acc.x=fmaf(c,h.x,acc.x); acc.y=fmaf(c,h.y,acc.y);
    acc.z=fmaf(c,h.z,acc.z); acc.w=fmaf(c,h.w,acc.w);
  }
  float dn = dinv[n];
  float sc = 2.f*dn*dn;
  float4 hn = ldU4(H, (size_t)n*F + q*4);
  float4 bv = *(const float4*)(bias + q*4);
  float4 o;
  o.x = eluf(fmaf(sc,hn.x,fmaf(dn,acc.x,bv.x)));
  o.y = eluf(fmaf(sc,hn.y,fmaf(dn,acc.y,bv.y)));
  o.z = eluf(fmaf(sc,hn.z,fmaf(dn,acc.z,bv.z)));
  o.w = eluf(fmaf(sc,hn.w,fmaf(dn,acc.w,bv.w)));
  stU4(OUT, (size_t)n*F + q*4, o);
  if (SCORE){
    float4 pv = *(const float4*)(p + q*4);
    float dot = o.x*pv.x + o.y*pv.y + o.z*pv.z + o.w*pv.w;
    float n2  = pv.x*pv.x + pv.y*pv.y + pv.z*pv.z + pv.w*pv.w;
    #pragma unroll
    for (int mk=FQ>>1; mk>0; mk>>=1){
      dot += __shfl_xor(dot, mk);
      n2  += __shfl_xor(n2,  mk);
    }
    if (q==0) score[n] = tanhf(dot * rsqrtf(n2));
  }
}

// ---- pooled-level GCN aggregation through rm filter (bf16 H/OUT)
template<int F, bool SCORE>
__global__ __launch_bounds__(256) void k_gather_rm(const int* __restrict__ orig,
    const int* __restrict__ rowptr0, const int* __restrict__ col0,
    const int* __restrict__ rm, const float* __restrict__ dinv,
    const unsigned short* __restrict__ H, const float* __restrict__ bias,
    unsigned short* __restrict__ OUT, int M,
    const float* __restrict__ p, float* __restrict__ score){
  constexpr int FQ = F/4;
  int i = blockIdx.x*256+threadIdx.x;
  if (i >= M*FQ) return;
  int n = i/FQ, q = i - (i/FQ)*FQ;
  int o = orig[n];
  int beg = rowptr0[o], end = rowptr0[o+1];
  float4 acc; acc.x=0.f;acc.y=0.f;acc.z=0.f;acc.w=0.f;
  for (int j=beg;j<end;++j){
    int s = rm[col0[j]];
    if (s >= 0){
      float c = dinv[s];
      float4 h = ldU4(H, (size_t)s*F + q*4);
      acc.x=fmaf(c,h.x,acc.x); acc.y=fmaf(c,h.y,acc.y);
      acc.z=fmaf(c,h.z,acc.z); acc.w=fmaf(c,h.w,acc.w);
    }
  }
  float dn = dinv[n];
  float sc = 2.f*dn*dn;
  float4 hn = ldU4(H, (size_t)n*F + q*4);
  float4 bv = *(const float4*)(bias + q*4);
  float4 ov;
  ov.x = eluf(fmaf(sc,hn.x,fmaf(dn,acc.x,bv.x)));
  ov.y = eluf(fmaf(sc,hn.y,fmaf(dn,acc.y,bv.y)));
  ov.z = eluf(fmaf(sc,hn.z,fmaf(dn,acc.z,bv.z)));
  ov.w = eluf(fmaf(sc,hn.w,fmaf(dn,acc.w,bv.w)));
  stU4(OUT, (size_t)n*F + q*4, ov);
  if (SCORE){
    float4 pv = *(const float4*)(p + q*4);
    float dot = ov.x*pv.x + ov.y*pv.y + ov.z*pv.z + ov.w*pv.w;
    float n2  = pv.x*pv.x + pv.y*pv.y + pv.z*pv.z + pv.w*pv.w;
    #pragma unroll
    for (int mk=FQ>>1; mk>0; mk>>=1){
      dot += __shfl_xor(dot, mk);
      n2  += __shfl_xor(n2,  mk);
    }
    if (q==0) score[n] = tanhf(dot * rsqrtf(n2));
  }
}

// per-graph global max/mean pool over (1024,32) bf16 x13, MLP head + log_softmax
__global__ void k_head(const unsigned short* __restrict__ x13, const float* __restrict__ Wl,
                       const float* __restrict__ Wc, const float* __restrict__ bc,
                       float* __restrict__ out){
  __shared__ float smax[256], ssum[256];
  __shared__ float gv[64], g2[64], logit[10];
  int g = blockIdx.x, t = threadIdx.x;
  int f = t & 31, r0 = t >> 5;
  float mx = -3.4e38f, sm = 0.f;
  const unsigned short* base = x13 + (size_t)g*N_*32;
  for (int r=r0; r<N_; r+=8){ float v = bf2f(base[r*32+f]); mx = fmaxf(mx,v); sm += v; }
  smax[t]=mx; ssum[t]=sm; __syncthreads();
  if (t<128){ smax[t]=fmaxf(smax[t],smax[t+128]); ssum[t]+=ssum[t+128]; } __syncthreads();
  if (t<64){ smax[t]=fmaxf(smax[t],smax[t+64]); ssum[t]+=ssum[t+64]; } __syncthreads();
  if (t<32){
    float m2 = fmaxf(smax[t],smax[t+32]); float s2 = ssum[t]+ssum[t+32];
    gv[t] = eluf(m2); gv[32+t] = eluf(s2 * (1.f/N_));
  }
  __syncthreads();
  if (t<64){
    float acc=0.f;
    #pragma unroll
    for (int i2=0;i2<64;++i2) acc = fmaf(gv[i2], Wl[i2*64+t], acc);
    g2[t] = eluf(acc);
  }
  __syncthreads();
  if (t<10){
    float acc = bc[t];
    #pragma unroll
    for (int j=0;j<64;++j) acc = fmaf(g2[j], Wc[j*10+t], acc);
    logit[t] = acc;
  }
  __syncthreads();
  if (t==0){
    float m=-3.4e38f; for (int c=0;c<10;++c) m=fmaxf(m,logit[c]);
    float s=0.f; for (int c=0;c<10;++c) s += expf(logit[c]-m);
    float lse = m + logf(s);
    for (int c=0;c<10;++c) out[g*10+c] = logit[c]-lse;
  }
}

extern "C" void kernel_launch(void* const* d_in, const int* in_sizes, int n_in,
                              void* d_out, int out_size, void* d_ws, size_t ws_size,
                              hipStream_t stream){
  const float* x  = (const float*)d_in[0];
  const float* W1 = (const float*)d_in[1];
  const float* b1 = (const float*)d_in[2];
  const float* p1 = (const float*)d_in[3];
  const float* W2 = (const float*)d_in[4];
  const float* b2 = (const float*)d_in[5];
  const float* p2 = (const float*)d_in[6];
  const float* W3 = (const float*)d_in[7];
  const float* b3 = (const float*)d_in[8];
  const float* p3 = (const float*)d_in[9];
  const float* W4 = (const float*)d_in[10];
  const float* b4 = (const float*)d_in[11];
  const float* W5 = (const float*)d_in[12];
  const float* b5 = (const float*)d_in[13];
  const float* W6 = (const float*)d_in[14];
  const float* b6 = (const float*)d_in[15];
  const float* W7 = (const float*)d_in[16];
  const float* b7 = (const float*)d_in[17];
  const float* Wl = (const float*)d_in[18];
  const float* Wc = (const float*)d_in[19];
  const float* bc = (const float*)d_in[20];
  const int* src0 = (const int*)d_in[21];
  const int* dst0 = (const int*)d_in[22];
  float* out = (float*)d_out;

  char* wsp = (char*)d_ws;
  size_t off = 0;
  auto alloc = [&](size_t bytes)->char*{
    char* p = wsp + off;
    off += (bytes + 255) & ~(size_t)255;
    return p;
  };
  unsigned short* bufA = (unsigned short*)alloc((size_t)2097152*2);  // x1 / x13
  unsigned short* bufB = (unsigned short*)alloc((size_t)2097152*2);  // x3
  unsigned short* bufC = (unsigned short*)alloc((size_t)2097152*2);  // x5 / x11
  unsigned short* bufD = (unsigned short*)alloc((size_t)2097152*2);  // x7 / x9
  unsigned short* bufH = (unsigned short*)alloc((size_t)2097152*2);  // pre-norm H
  float* score= (float*)alloc((size_t)M0_*4);
  float* vals2= (float*)alloc((size_t)M1_*4);
  float* vals4= (float*)alloc((size_t)M2_*4);
  float* vals6= (float*)alloc((size_t)M3_*4);
  int* idx2 = (int*)alloc((size_t)M1_*4);
  int* idx4 = (int*)alloc((size_t)M2_*4);
  int* idx6 = (int*)alloc((size_t)M3_*4);
  int* orig4 = (int*)alloc((size_t)M2_*4);
  int* orig6 = (int*)alloc((size_t)M3_*4);
  int* rm02 = (int*)alloc((size_t)M0_*4);
  int* rm04 = (int*)alloc((size_t)M0_*4);
  int* rm06 = (int*)alloc((size_t)M0_*4);
  int* col0 = (int*)alloc((size_t)E_*4);
  int* rowptr0 = (int*)alloc((size_t)(M0_+1)*4);
  float* dinv0 = (float*)alloc((size_t)M0_*4);
  float* dinv2 = (float*)alloc((size_t)M1_*4);
  float* dinv4 = (float*)alloc((size_t)M2_*4);
  float* dinv6 = (float*)alloc((size_t)M3_*4);

  auto NB = [](int total){ return (total+255)/256; };

  // ---- fused: layer-1 GEMM (blocks 0-511) ∥ per-graph CSR (blocks 512-575)
  k_csr_mm1<<<576,256,0,stream>>>(x, W1, bufH, src0, dst0, rowptr0, col0, dinv0);

  // ---- x1 = gather(H1) + fused score1
  k_gather<32,true><<<NB(M0_*8),256,0,stream>>>(rowptr0, col0, dinv0, bufH, b1, bufA, M0_, p1, score);

  // ---- pool 1 (standalone — r17 proved fence fusion regresses)
  k_pool<<<B_,1024,0,stream>>>(score, 1024, K1_, nullptr, rowptr0, col0,
      idx2, vals2, idx2, rm02, dinv2);

  // ---- layer 2 (fused pool staging) -> x3 (bufB) + score2
  k_mm<64,64,1><<<dim3(M1_/64,1),256,0,stream>>>(bufA, W2, bufH, M1_, 32, 64,
      idx2, vals2, nullptr,nullptr,nullptr,0);
  k_gather_rm<64,true><<<NB(M1_*16),256,0,stream>>>(idx2, rowptr0, col0, rm02, dinv2, bufH, b2, bufB, M1_, p2, score);

  // ---- pool 2
  k_pool<<<B_,512,0,stream>>>(score, 512, K2_, idx2, rowptr0, col0,
      idx4, vals4, orig4, rm04, dinv4);

  // ---- layer 3 -> x5 (bufC) + score3
  k_mm<64,64,1><<<dim3(M2_/64,2),256,0,stream>>>(bufB, W3, bufH, M2_, 64, 128,
      idx4, vals4, nullptr,nullptr,nullptr,0);
  k_gather_rm<128,true><<<NB(M2_*32),256,0,stream>>>(orig4, rowptr0, col0, rm04, dinv4, bufH, b3, bufC, M2_, p3, score);

  // ---- pool 3
  k_pool<<<B_,256,0,stream>>>(score, 256, K3_, orig4, rowptr0, col0,
      idx6, vals6, orig6, rm06, dinv6);

  // ---- layer 4 -> x7 (bufD)
  k_mm<64,64,1><<<dim3(M3_/64,4),256,0,stream>>>(bufC, W4, bufH, M3_, 128, 256,
      idx6, vals6, nullptr,nullptr,nullptr,0);
  k_gather_rm<256,false><<<NB(M3_*64),256,0,stream>>>(orig6, rowptr0, col0, rm06, dinv6, bufH, b4, bufD, M3_, nullptr, nullptr);

  // ---- layer 5 (fused concat staging) -> x9 (bufD)
  k_mm<64,64,2><<<dim3(M2_/64,2),256,0,stream>>>(bufC, W5, bufH, M2_, 384, 128,
      nullptr,nullptr, bufD, orig4, rm06, 64);
  k_gather_rm<128,false><<<NB(M2_*32),256,0,stream>>>(orig4, rowptr0, col0, rm04, dinv4, bufH, b5, bufD, M2_, nullptr, nullptr);

  // ---- layer 6 -> x11 (bufC)
  k_mm<64,64,2><<<dim3(M1_/64,1),256,0,stream>>>(bufB, W6, bufH, M1_, 192, 64,
      nullptr,nullptr, bufD, idx2, rm04, 32);
  k_gather_rm<64,false><<<NB(M1_*16),256,0,stream>>>(idx2, rowptr0, col0, rm02, dinv2, bufH, b6, bufC, M1_, nullptr, nullptr);

  // ---- layer 7 -> x13 (bufA)
  k_mm<128,32,2><<<dim3(M0_/128,1),256,0,stream>>>(bufA, W7, bufH, M0_, 96, 32,
      nullptr,nullptr, bufC, nullptr, rm02, 16);
  k_gather<32,false><<<NB(M0_*8),256,0,stream>>>(rowptr0, col0, dinv0, bufH, b7, bufA, M0_, nullptr, nullptr);

  // ---- head
  k_head<<<B_,256,0,stream>>>(bufA, Wl, Wc, bc, out);

  (void)in_sizes; (void)n_in; (void)out_size; (void)ws_size;
}